// Round 8
// baseline (7266.447 us; speedup 1.0000x reference)
//
#include <hip/hip_runtime.h>
#include <hip/hip_bf16.h>

// Two-layer tanh RNN, B=32 T=512 I=512 H=1024, fp32 in/out, bf16 MFMA.
// Round-8 = round-7 design with the compile fix (stray '#pragma unroll'
// before a non-loop brace block removed). XCD-LOCAL RECURRENCE:
//   - Layer 0 runs entirely on XCD 0 (32 WGs/CUs), layer 1 on XCD 1.
//     WGs discover their XCD via s_getreg(HW_REG_XCC_ID=20) and claim a
//     32-column slice via a per-XCD atomic counter. 256 WGs x 96KB LDS
//     force 1 WG/CU -> exactly 32 WGs per XCD.
//   - Intra-XCD h exchange: plain stores + sc0 loads/polls (L1-bypass,
//     L2-coherent within an XCD, ~200cy RT) -- replaces rounds 1-6's
//     ~900cy L3 hops on the serial path.
//   - Cross-XCD (h1 -> L1) is PIPELINED through a 64-slot L3 ring with
//     lazy back-pressure; its latency is off the critical path.
//   - Weights in VGPRs (B-fragments, loaded once); 32x32x16 MFMA (2x FLOP
//     per operand byte vs 16x16x32); 4-way K-split per WG + LDS reduce.
//   - Idle 6 XCDs run a VALU heater (DVFS) until 'done'; all polls have
//     abort timeouts so nothing can hang the bench.

#define B_ 32
#define T_ 512
#define I_ 512
#define H_ 1024

typedef __attribute__((ext_vector_type(8))) short short8;
typedef __attribute__((ext_vector_type(16))) float float16v;

// ---- workspace layout (bytes) ----
#define OFF_XBF  0ull            // x bf16 [B][T][I]          16,777,216
#define OFF_H1G  16777216ull     // h1 L3 ring, 64 x 65536B    4,194,304
#define OFF_H1L  20971520ull     // h1 local ring, 4 x 65536B    262,144
#define OFF_H2L  21233664ull     // h2 local ring, 4 x 65536B    262,144
#define OFF_LF0  21495808ull     // L0 local flags 128 x 64B       8,192
#define OFF_LF1  21504000ull     // L1 local flags 128 x 64B       8,192
#define OFF_GF   21512192ull     // global (L3) flags 128 x 64B    8,192
#define OFF_MISC 21520384ull     // l1prog@0, done@64, abort@96, claims@128+64*x

#define WAIT_VM0() asm volatile("s_waitcnt vmcnt(0)" ::: "memory")

#define LDF0(f, base, O) \
  asm volatile("global_load_dwordx4 %0, %1, off offset:%2 sc0" \
               : "=v"(f) : "v"(base), "n"(O) : "memory")
#define LDF1(f, base, O) \
  asm volatile("global_load_dwordx4 %0, %1, off offset:%2 sc1" \
               : "=v"(f) : "v"(base), "n"(O) : "memory")

#define VMW8(N, F, S) \
  asm volatile("s_waitcnt vmcnt(" #N ")" \
               : "+v"(F[S+0]), "+v"(F[S+1]), "+v"(F[S+2]), "+v"(F[S+3]), \
                 "+v"(F[S+4]), "+v"(F[S+5]), "+v"(F[S+6]), "+v"(F[S+7]))

#define STF_SC0(p, v) \
  asm volatile("global_store_dword %0, %1, off sc0" :: "v"(p), "v"(v) : "memory")

// tanh via exp2+rcp (round-4 proven numerics).
__device__ __forceinline__ float fast_tanh(float x) {
  float z = fminf(2.885390081777927f * x, 60.0f);
  float e = __builtin_amdgcn_exp2f(z);
  return 1.0f - 2.0f * __builtin_amdgcn_rcpf(e + 1.0f);
}

// Poll all 128 flags (two per lane) until >= s. sc0 = intra-XCD (L2),
// sc1 = cross-XCD (L3). Abort-timeout so a broken assumption cannot hang.
#define DEF_POLL(NAME, SC) \
__device__ __forceinline__ void NAME(const unsigned* base, int lane, unsigned s, \
                                     unsigned* abortf) { \
  const unsigned* p1 = base + (unsigned)lane * 16u; \
  const unsigned* p2 = base + ((unsigned)lane + 64u) * 16u; \
  unsigned it = 0; \
  for (;;) { \
    unsigned a, b; \
    asm volatile("global_load_dword %0, %2, off " SC "\n\t" \
                 "global_load_dword %1, %3, off " SC "\n\t" \
                 "s_waitcnt vmcnt(0)" \
                 : "=v"(a), "=v"(b) : "v"(p1), "v"(p2) : "memory"); \
    if (__all((int)(a >= s && b >= s))) return; \
    if ((++it & 63u) == 0u) { \
      if (it > 200000u) { \
        __hip_atomic_store(abortf, 1u, __ATOMIC_RELAXED, __HIP_MEMORY_SCOPE_AGENT); \
        return; \
      } \
      if (__hip_atomic_load(abortf, __ATOMIC_RELAXED, __HIP_MEMORY_SCOPE_AGENT)) return; \
    } \
  } \
}
DEF_POLL(poll128_sc0, "sc0")
DEF_POLL(poll128_sc1, "sc1")

__device__ __forceinline__ short8 pack8(float4 a, float4 b) {
  __hip_bfloat16 t[8];
  t[0] = __float2bfloat16(a.x); t[1] = __float2bfloat16(a.y);
  t[2] = __float2bfloat16(a.z); t[3] = __float2bfloat16(a.w);
  t[4] = __float2bfloat16(b.x); t[5] = __float2bfloat16(b.y);
  t[6] = __float2bfloat16(b.z); t[7] = __float2bfloat16(b.w);
  short8 r;
#pragma unroll
  for (int i = 0; i < 8; ++i) r[i] = *reinterpret_cast<short*>(&t[i]);
  return r;
}

#define MFMA32(acc, a, b) \
  acc = __builtin_amdgcn_mfma_f32_32x32x16_bf16(a, b, acc, 0, 0, 0)

__global__ __launch_bounds__(256, 1)
void rnn_kernel(const float* __restrict__ Wih0, const float* __restrict__ Whh0,
                const float* __restrict__ bih0, const float* __restrict__ bhh0,
                const float* __restrict__ Wih1, const float* __restrict__ Whh1,
                const float* __restrict__ bih1, const float* __restrict__ bhh1,
                const __hip_bfloat16* __restrict__ x_bf,
                char* __restrict__ ws, float* __restrict__ out)
{
  // 96KB LDS (16KB+pad used for the K-split reduce) -> 1 WG/CU, so a 256-WG
  // grid places exactly 32 WGs on each of the 8 XCDs.
  __shared__ float redbuf[24576];
  __shared__ int s_slice;

  __hip_bfloat16* h1g = (__hip_bfloat16*)(ws + OFF_H1G);
  __hip_bfloat16* h1l = (__hip_bfloat16*)(ws + OFF_H1L);
  __hip_bfloat16* h2l = (__hip_bfloat16*)(ws + OFF_H2L);
  unsigned* lf0 = (unsigned*)(ws + OFF_LF0);
  unsigned* lf1 = (unsigned*)(ws + OFF_LF1);
  unsigned* gf  = (unsigned*)(ws + OFF_GF);
  unsigned* misc = (unsigned*)(ws + OFF_MISC);
  unsigned* l1prog = misc;           // +0
  unsigned* done   = misc + 16;      // +64B
  unsigned* abortf = misc + 24;      // +96B
  unsigned* claims = misc + 32;      // +128B, claims[xcd] at +32+16*xcd dwords

  int xcd;
  asm volatile("s_getreg_b32 %0, hwreg(20, 0, 32)" : "=s"(xcd));  // HW_REG_XCC_ID
  xcd &= 7;

  if (threadIdx.x == 0) {
    int sl = -1;
    if (xcd <= 1) sl = (int)atomicAdd(claims + xcd * 16, 1u);
    s_slice = sl;
  }
  __syncthreads();
  const int sl = s_slice;

  if (xcd > 1 || sl < 0 || sl >= 32) {
    // -------- heater: keep DVFS clocks up on the 6 idle XCDs --------
    unsigned long long t0 = __builtin_amdgcn_s_memrealtime();  // 100 MHz
    float a = 1.0f, b = 1.0000001f, c = 0.9999999f;
    for (;;) {
#pragma unroll 64
      for (int i = 0; i < 512; ++i)
        asm volatile("v_fmac_f32 %0, %1, %2" : "+v"(a) : "v"(b), "v"(c));
      unsigned d;
      asm volatile("global_load_dword %0, %1, off sc1\n\ts_waitcnt vmcnt(0)"
                   : "=v"(d) : "v"(done) : "memory");
      if (d) break;
      if (__builtin_amdgcn_s_memrealtime() - t0 > 400000000ull) break;  // 4s cap
    }
    return;
  }

  const int tid  = threadIdx.x;
  const int lane = tid & 63;
  const int w    = tid >> 6;         // wave = K-slice owner
  const int kgrp = lane >> 5;        // A/B fragment k-subgroup (0/1)
  const int brow = lane & 31;        // A row = batch index
  const int col  = sl * 32 + (lane & 31);
  const int colp = col & ~1;
  const int r0   = (lane & 1) ? 2 : 0;  // reg pair this lane stores

  if (xcd == 0) {
    // ==================== LAYER 0 (XCD 0) ====================
    const float bias = bih0[col] + bhh0[col];
    unsigned* myf  = lf0 + (sl * 4 + w) * 16;
    unsigned* mygf = gf  + (sl * 4 + w) * 16;
    // Weights -> VGPR B-fragments (once). B[k][col], k = kb*16 + kgrp*8 + j.
    short8 Bx[8], Bh[16];
#pragma unroll
    for (int i = 0; i < 8; ++i) {
      int k = (w * 8 + i) * 16 + kgrp * 8;
      const float4* p = (const float4*)(Wih0 + (size_t)col * I_ + k);
      Bx[i] = pack8(p[0], p[1]);
    }
#pragma unroll
    for (int i = 0; i < 16; ++i) {
      int k = (w * 16 + i) * 16 + kgrp * 8;
      const float4* p = (const float4*)(Whh0 + (size_t)col * H_ + k);
      Bh[i] = pack8(p[0], p[1]);
    }
    unsigned cached_prog = 0;

    for (int s = 0; s < T_; ++s) {
      float16v acc = {0,0,0,0,0,0,0,0,0,0,0,0,0,0,0,0};
      // x-projection: plain cached loads, independent of the flag wait.
      const __hip_bfloat16* xb =
          x_bf + (size_t)brow * (T_ * I_) + (size_t)s * I_ + kgrp * 8;
#pragma unroll
      for (int i = 0; i < 8; ++i) {
        short8 a = *(const short8*)(xb + (w * 8 + i) * 16);
        MFMA32(acc, a, Bx[i]);
      }
      if (s > 0) poll128_sc0(lf0, lane, (unsigned)s, abortf);
      // h1[s] fragments from local ring (L2-coherent sc0 loads).
      const __hip_bfloat16* hb = h1l + (size_t)(s & 3) * (B_ * H_)
                               + (size_t)brow * H_ + w * 256 + kgrp * 8;
      short8 Ah[16];
      { LDF0(Ah[0], hb, 0);   LDF0(Ah[1], hb, 32);  LDF0(Ah[2], hb, 64);
        LDF0(Ah[3], hb, 96);  LDF0(Ah[4], hb, 128); LDF0(Ah[5], hb, 160);
        LDF0(Ah[6], hb, 192); LDF0(Ah[7], hb, 224); LDF0(Ah[8], hb, 256);
        LDF0(Ah[9], hb, 288); LDF0(Ah[10], hb, 320); LDF0(Ah[11], hb, 352);
        LDF0(Ah[12], hb, 384); LDF0(Ah[13], hb, 416); LDF0(Ah[14], hb, 448);
        LDF0(Ah[15], hb, 480); }
      VMW8(8, Ah, 0);
#pragma unroll
      for (int i = 0; i < 8; ++i) MFMA32(acc, Ah[i], Bh[i]);
      VMW8(0, Ah, 8);
#pragma unroll
      for (int i = 8; i < 16; ++i) MFMA32(acc, Ah[i], Bh[i]);
      // K-split reduce across the 4 waves via LDS (bank-conflict-free b32).
#pragma unroll
      for (int r = 0; r < 16; ++r) redbuf[r * 257 + w * 64 + lane] = acc[r];
      __syncthreads();
      float4 sum = {bias, bias, bias, bias};
#pragma unroll
      for (int w2 = 0; w2 < 4; ++w2) {
        sum.x += redbuf[(w * 4 + 0) * 257 + w2 * 64 + lane];
        sum.y += redbuf[(w * 4 + 1) * 257 + w2 * 64 + lane];
        sum.z += redbuf[(w * 4 + 2) * 257 + w2 * 64 + lane];
        sum.w += redbuf[(w * 4 + 3) * 257 + w2 * 64 + lane];
      }
      float hv[4] = {fast_tanh(sum.x), fast_tanh(sum.y),
                     fast_tanh(sum.z), fast_tanh(sum.w)};
      // Back-pressure on the L3 ring (binds only if L0 is 60+ steps ahead).
      unsigned bpit = 0;
      while ((unsigned)(s + 1) - cached_prog > 60u) {
        cached_prog = __hip_atomic_load(l1prog, __ATOMIC_RELAXED, __HIP_MEMORY_SCOPE_AGENT);
        if ((unsigned)(s + 1) - cached_prog > 60u) {
          __builtin_amdgcn_s_sleep(8);
          if (++bpit > 2000000u) break;
        }
      }
      __hip_bfloat16* hl = h1l + (size_t)((s + 1) & 3) * (B_ * H_);
      unsigned* hgd = (unsigned*)(h1g + (size_t)((s + 1) & 63) * (B_ * H_));
#pragma unroll
      for (int j = 0; j < 4; ++j) {
        float other = __shfl_xor(hv[j], 1, 64);
        float lo = (lane & 1) ? other : hv[j];
        float hi = (lane & 1) ? hv[j] : other;
        if (j == r0 || j == r0 + 1) {
          int row = 8 * w + 4 * kgrp + j;   // C row = (reg&3)+8*(reg>>2)+4*(lane>>5)
          __hip_bfloat16 l16 = __float2bfloat16(lo), h16 = __float2bfloat16(hi);
          unsigned pk = (unsigned)*(unsigned short*)&l16
                      | ((unsigned)*(unsigned short*)&h16 << 16);
          *(unsigned*)(hl + (size_t)row * H_ + colp) = pk;             // local (L2)
          __hip_atomic_store(hgd + ((row * H_ + colp) >> 1), pk,       // L3 ring
                             __ATOMIC_RELAXED, __HIP_MEMORY_SCOPE_AGENT);
        }
      }
      WAIT_VM0();   // h stores acked (L2 + L3)
      if (lane == 0) {
        STF_SC0(myf, (unsigned)(s + 1));
        __hip_atomic_store(mygf, (unsigned)(s + 1), __ATOMIC_RELAXED, __HIP_MEMORY_SCOPE_AGENT);
      }
    }
  } else {
    // ==================== LAYER 1 (XCD 1) ====================
    const float bias = bih1[col] + bhh1[col];
    unsigned* myf = lf1 + (sl * 4 + w) * 16;
    short8 Bin[16], Bh2[16];
#pragma unroll
    for (int i = 0; i < 16; ++i) {
      int k = (w * 16 + i) * 16 + kgrp * 8;
      const float4* p = (const float4*)(Wih1 + (size_t)col * H_ + k);
      Bin[i] = pack8(p[0], p[1]);
      const float4* q = (const float4*)(Whh1 + (size_t)col * H_ + k);
      Bh2[i] = pack8(q[0], q[1]);
    }

    for (int t = 0; t < T_; ++t) {
      // h1[t+1] from the L3 ring: L0 runs ahead, so this wait is ~one L3 RT.
      poll128_sc1(gf, lane, (unsigned)(t + 1), abortf);
      const __hip_bfloat16* ib = h1g + (size_t)((t + 1) & 63) * (B_ * H_)
                               + (size_t)brow * H_ + w * 256 + kgrp * 8;
      short8 Ain[16];
      { LDF1(Ain[0], ib, 0);   LDF1(Ain[1], ib, 32);  LDF1(Ain[2], ib, 64);
        LDF1(Ain[3], ib, 96);  LDF1(Ain[4], ib, 128); LDF1(Ain[5], ib, 160);
        LDF1(Ain[6], ib, 192); LDF1(Ain[7], ib, 224); LDF1(Ain[8], ib, 256);
        LDF1(Ain[9], ib, 288); LDF1(Ain[10], ib, 320); LDF1(Ain[11], ib, 352);
        LDF1(Ain[12], ib, 384); LDF1(Ain[13], ib, 416); LDF1(Ain[14], ib, 448);
        LDF1(Ain[15], ib, 480); }
      // local h2 wait (vmcnt(0) inside also drains the Ain loads)
      poll128_sc0(lf1, lane, (unsigned)t, abortf);
      const __hip_bfloat16* hb = h2l + (size_t)(t & 3) * (B_ * H_)
                               + (size_t)brow * H_ + w * 256 + kgrp * 8;
      short8 Ah[16];
      { LDF0(Ah[0], hb, 0);   LDF0(Ah[1], hb, 32);  LDF0(Ah[2], hb, 64);
        LDF0(Ah[3], hb, 96);  LDF0(Ah[4], hb, 128); LDF0(Ah[5], hb, 160);
        LDF0(Ah[6], hb, 192); LDF0(Ah[7], hb, 224); LDF0(Ah[8], hb, 256);
        LDF0(Ah[9], hb, 288); LDF0(Ah[10], hb, 320); LDF0(Ah[11], hb, 352);
        LDF0(Ah[12], hb, 384); LDF0(Ah[13], hb, 416); LDF0(Ah[14], hb, 448);
        LDF0(Ah[15], hb, 480); }
      float16v acc = {0,0,0,0,0,0,0,0,0,0,0,0,0,0,0,0};
#pragma unroll
      for (int i = 0; i < 16; ++i) MFMA32(acc, Ain[i], Bin[i]);   // overlaps Ah
      VMW8(8, Ah, 0);
#pragma unroll
      for (int i = 0; i < 8; ++i) MFMA32(acc, Ah[i], Bh2[i]);
      VMW8(0, Ah, 8);
#pragma unroll
      for (int i = 8; i < 16; ++i) MFMA32(acc, Ah[i], Bh2[i]);
#pragma unroll
      for (int r = 0; r < 16; ++r) redbuf[r * 257 + w * 64 + lane] = acc[r];
      __syncthreads();
      float4 sum = {bias, bias, bias, bias};
#pragma unroll
      for (int w2 = 0; w2 < 4; ++w2) {
        sum.x += redbuf[(w * 4 + 0) * 257 + w2 * 64 + lane];
        sum.y += redbuf[(w * 4 + 1) * 257 + w2 * 64 + lane];
        sum.z += redbuf[(w * 4 + 2) * 257 + w2 * 64 + lane];
        sum.w += redbuf[(w * 4 + 3) * 257 + w2 * 64 + lane];
      }
      float hv[4] = {fast_tanh(sum.x), fast_tanh(sum.y),
                     fast_tanh(sum.z), fast_tanh(sum.w)};
      __hip_bfloat16* hl = h2l + (size_t)((t + 1) & 3) * (B_ * H_);
      float lov[4], hiv[4];
#pragma unroll
      for (int j = 0; j < 4; ++j) {
        float other = __shfl_xor(hv[j], 1, 64);
        lov[j] = (lane & 1) ? other : hv[j];
        hiv[j] = (lane & 1) ? hv[j] : other;
        if (j == r0 || j == r0 + 1) {
          int row = 8 * w + 4 * kgrp + j;
          __hip_bfloat16 l16 = __float2bfloat16(lov[j]), h16 = __float2bfloat16(hiv[j]);
          unsigned pk = (unsigned)*(unsigned short*)&l16
                      | ((unsigned)*(unsigned short*)&h16 << 16);
          *(unsigned*)(hl + (size_t)row * H_ + colp) = pk;
        }
      }
      WAIT_VM0();
      if (lane == 0) STF_SC0(myf, (unsigned)(t + 1));
      // fp32 output after the flag: off the serial path.
#pragma unroll
      for (int j = 0; j < 4; ++j) {
        if (j == r0 || j == r0 + 1) {
          int row = 8 * w + 4 * kgrp + j;
          float2 f2; f2.x = lov[j]; f2.y = hiv[j];
          *(float2*)(out + (size_t)row * (T_ * H_) + (size_t)t * H_ + colp) = f2;
        }
      }
      if (sl == 0 && w == 0 && lane == 0)
        __hip_atomic_store(l1prog, (unsigned)(t + 1), __ATOMIC_RELAXED, __HIP_MEMORY_SCOPE_AGENT);
    }
    if (sl == 0 && w == 0 && lane == 0)
      __hip_atomic_store(done, 1u, __ATOMIC_RELAXED, __HIP_MEMORY_SCOPE_AGENT);
  }
}

// Re-init every call (ws poisoned 0xAA by harness). Bounds exact (round-5 lesson).
__global__ void prep_kernel(const float* __restrict__ x, unsigned long long* __restrict__ x64,
                            unsigned* __restrict__ h1l, unsigned* __restrict__ h2l,
                            unsigned* __restrict__ lf0, unsigned* __restrict__ lf1,
                            unsigned* __restrict__ gf, unsigned* __restrict__ misc)
{
  unsigned i = blockIdx.x * 256 + threadIdx.x;
  if (i < 2097152u) {                      // B*T*I/4 float4 elements
    const float4* x4 = (const float4*)x;
    float4 v = x4[i];
    __hip_bfloat16 b0 = __float2bfloat16(v.x), b1 = __float2bfloat16(v.y);
    __hip_bfloat16 b2 = __float2bfloat16(v.z), b3 = __float2bfloat16(v.w);
    unsigned long long r = (unsigned long long)*(unsigned short*)&b0
                         | ((unsigned long long)*(unsigned short*)&b1 << 16)
                         | ((unsigned long long)*(unsigned short*)&b2 << 32)
                         | ((unsigned long long)*(unsigned short*)&b3 << 48);
    x64[i] = r;
  }
  if (i < 16384u) h1l[i] = 0u;   // h1 local ring slot 0 = H1[0] = zeros
  if (i < 16384u) h2l[i] = 0u;   // h2 local ring slot 0
  if (i < 2048u)  lf0[i] = 0u;
  if (i < 2048u)  lf1[i] = 0u;
  if (i < 2048u)  gf[i]  = 0u;
  if (i < 256u)   misc[i] = 0u;  // l1prog, done, abort, claims
}

extern "C" void kernel_launch(void* const* d_in, const int* in_sizes, int n_in,
                              void* d_out, int out_size, void* d_ws, size_t ws_size,
                              hipStream_t stream)
{
  const float* x    = (const float*)d_in[0];
  const float* Wih0 = (const float*)d_in[1];
  const float* Whh0 = (const float*)d_in[2];
  const float* bih0 = (const float*)d_in[3];
  const float* bhh0 = (const float*)d_in[4];
  const float* Wih1 = (const float*)d_in[5];
  const float* Whh1 = (const float*)d_in[6];
  const float* bih1 = (const float*)d_in[7];
  const float* bhh1 = (const float*)d_in[8];
  float* out = (float*)d_out;
  char* ws = (char*)d_ws;

  __hip_bfloat16* x_bf = (__hip_bfloat16*)(ws + OFF_XBF);

  prep_kernel<<<8192, 256, 0, stream>>>(
      x, (unsigned long long*)x_bf,
      (unsigned*)(ws + OFF_H1L), (unsigned*)(ws + OFF_H2L),
      (unsigned*)(ws + OFF_LF0), (unsigned*)(ws + OFF_LF1),
      (unsigned*)(ws + OFF_GF),  (unsigned*)(ws + OFF_MISC));

  // 256 WGs x 256 thr, 96KB LDS -> 1 WG/CU -> exactly 32 WGs per XCD.
  rnn_kernel<<<256, 256, 0, stream>>>(Wih0, Whh0, bih0, bhh0,
                                      Wih1, Whh1, bih1, bhh1,
                                      x_bf, ws, out);
}